// Round 3
// baseline (159.812 us; speedup 1.0000x reference)
//
#include <hip/hip_runtime.h>
#include <hip/hip_bf16.h>

#define NROWS 65536
#define DIM   256
#define KC    512
#define ALPHA 0.05f

typedef __attribute__((ext_vector_type(8))) short bf16x8;
typedef __attribute__((ext_vector_type(4))) float f32x4;

static __device__ __forceinline__ unsigned short f2bf(float f) {
    union { __hip_bfloat16 h; unsigned short u; } c;
    c.h = __float2bfloat16(f);
    return c.u;
}
static __device__ __forceinline__ float bf2f(unsigned short u) {
    union { unsigned short u; __hip_bfloat16 h; } c;
    c.u = u;
    return __bfloat162float(c.h);
}

// Fragment-major center layout (verified): col-group cg (16 centers), k-step kk,
// lane l = q*16+m holds center row cg*16+m, elems kk*32+q*8 .. +7 (16 B).
// uint4 index = (cg*8+kk)*64 + l.  (cg = ch*4+w of the original indexing.)
__global__ void prep_centers(const float* __restrict__ centers,
                             float* __restrict__ csqh,
                             uint4* __restrict__ cbf2,
                             float* __restrict__ out) {
    const int t = threadIdx.x;
    const int r = blockIdx.x * 8 + (t >> 5);  // center row
    const int e = t & 31;                     // 8-elem group within row
    const float4* cv = reinterpret_cast<const float4*>(centers);
    float4 v0 = cv[r * 64 + e * 2];
    float4 v1 = cv[r * 64 + e * 2 + 1];
    float s = v0.x * v0.x + v0.y * v0.y + v0.z * v0.z + v0.w * v0.w
            + v1.x * v1.x + v1.y * v1.y + v1.z * v1.z + v1.w * v1.w;
    unsigned short o[8];
    o[0] = f2bf(v0.x); o[1] = f2bf(v0.y); o[2] = f2bf(v0.z); o[3] = f2bf(v0.w);
    o[4] = f2bf(v1.x); o[5] = f2bf(v1.y); o[6] = f2bf(v1.z); o[7] = f2bf(v1.w);
    const int cg = r >> 4, m = r & 15;
    const int kk = e >> 2, q = e & 3, l = q * 16 + m;
    cbf2[(cg * 8 + kk) * 64 + l] = *reinterpret_cast<uint4*>(o);
    #pragma unroll
    for (int off = 16; off; off >>= 1) s += __shfl_xor(s, off, 64);
    if (e == 0) csqh[r] = 0.5f * s;
    if (blockIdx.x == 0 && t == 0) out[0] = 0.f;  // separate dispatch -> ordered
}

// TLP-first design: no LDS for A, no DMA. Each wave: 32 rows x 256 centers,
// A direct global->reg (bf16 cvt in-reg), B streamed from L1/L2 with 1-deep
// register prefetch. One __syncthreads per block (tiny max/x2 combine).
// launch_bounds(256,3): target <=170 VGPR -> 3 waves/SIMD, 12 waves/CU.
__global__ __launch_bounds__(256, 3) void kmeans_main(
    const float* __restrict__ emb,
    const uint4* __restrict__ cbf2,
    const float* __restrict__ csqh_g,
    float* __restrict__ out) {
    __shared__ float lmax[4][32];   // per-wave row maxima
    __shared__ float lx2[64];       // per-row x^2 (bf16-consistent)

    const int t = threadIdx.x;
    const int w = t >> 6;           // wave 0..3
    const int lane = t & 63;
    const int m = lane & 15;
    const int q = lane >> 4;
    // w0: rows +0,  centers 0-255 | w1: rows +0,  centers 256-511
    // w2: rows +32, centers 0-255 | w3: rows +32, centers 256-511
    const int rowbase = blockIdx.x * 64 + (w >> 1) * 32;
    const int cgbase  = (w & 1) * 16;
    const bool do_x2  = (w & 1) == 0;   // wave-uniform: skip redundant x^2

    // ---- A: global -> reg fragments (rows rowbase+rt*16+m, elems kk*32+q*8) ----
    bf16x8 afr[2][8];
    float x2v[2];
    #pragma unroll
    for (int rt = 0; rt < 2; ++rt) {
        const float* rp = emb + (size_t)(rowbase + rt * 16 + m) * DIM + q * 8;
        float xs = 0.f;
        #pragma unroll
        for (int kk = 0; kk < 8; ++kk) {
            f32x4 v0 = *reinterpret_cast<const f32x4*>(rp + kk * 32);
            f32x4 v1 = *reinterpret_cast<const f32x4*>(rp + kk * 32 + 4);
            unsigned short o[8];
            o[0] = f2bf(v0.x); o[1] = f2bf(v0.y); o[2] = f2bf(v0.z); o[3] = f2bf(v0.w);
            o[4] = f2bf(v1.x); o[5] = f2bf(v1.y); o[6] = f2bf(v1.z); o[7] = f2bf(v1.w);
            afr[rt][kk] = *reinterpret_cast<bf16x8*>(o);
            if (do_x2) {
                #pragma unroll
                for (int j = 0; j < 8; ++j) { float f = bf2f(o[j]); xs += f * f; }
            }
        }
        if (do_x2) {
            xs += __shfl_xor(xs, 16, 64);   // sum over q (lanes m, m+16, m+32, m+48)
            xs += __shfl_xor(xs, 32, 64);
            x2v[rt] = xs;
        }
        // bound register pressure: keep the two rt load/cvt batches separate
        __builtin_amdgcn_sched_barrier(0);
    }
    if (do_x2 && q == 0) {
        lx2[(w >> 1) * 32 + m]      = x2v[0];
        lx2[(w >> 1) * 32 + 16 + m] = x2v[1];
    }

    // ---- stream 16 col-groups: B frags from L1/L2, 1-deep prefetch ----
    const bf16x8* cb2 = reinterpret_cast<const bf16x8*>(cbf2);
    float maxv[2][4];
    #pragma unroll
    for (int rt = 0; rt < 2; ++rt)
        #pragma unroll
        for (int rg = 0; rg < 4; ++rg) maxv[rt][rg] = -1e30f;

    float c2cur = csqh_g[cgbase * 16 + m];   // c^2/2 of center cg*16+m
    bf16x8 bcur[8];
    #pragma unroll
    for (int kk = 0; kk < 8; ++kk)
        bcur[kk] = cb2[((cgbase + 0) * 8 + kk) * 64 + lane];

    #pragma unroll
    for (int i = 0; i < 16; ++i) {
        bf16x8 bnxt[8];
        float c2n = 0.f;
        if (i < 15) {
            c2n = csqh_g[(cgbase + i + 1) * 16 + m];
            #pragma unroll
            for (int kk = 0; kk < 8; ++kk)
                bnxt[kk] = cb2[((cgbase + i + 1) * 8 + kk) * 64 + lane];
        }
        const float ci = -c2cur;
        f32x4 acc[2];
        acc[0] = (f32x4){ci, ci, ci, ci};
        acc[1] = (f32x4){ci, ci, ci, ci};
        #pragma unroll
        for (int kk = 0; kk < 8; ++kk)
            #pragma unroll
            for (int rt = 0; rt < 2; ++rt)
                acc[rt] = __builtin_amdgcn_mfma_f32_16x16x32_bf16(
                    afr[rt][kk], bcur[kk], acc[rt], 0, 0, 0);
        #pragma unroll
        for (int rt = 0; rt < 2; ++rt)
            #pragma unroll
            for (int rg = 0; rg < 4; ++rg)
                maxv[rt][rg] = fmaxf(maxv[rt][rg], acc[rt][rg]);
        if (i < 15) {
            #pragma unroll
            for (int kk = 0; kk < 8; ++kk) bcur[kk] = bnxt[kk];
            c2cur = c2n;
        }
    }

    // ---- per-wave max over its 16 cols (xor over lane&15); rows = q*4+rg ----
    #pragma unroll
    for (int rt = 0; rt < 2; ++rt)
        #pragma unroll
        for (int rg = 0; rg < 4; ++rg) {
            float v = maxv[rt][rg];
            v = fmaxf(v, __shfl_xor(v, 1, 64));
            v = fmaxf(v, __shfl_xor(v, 2, 64));
            v = fmaxf(v, __shfl_xor(v, 4, 64));
            v = fmaxf(v, __shfl_xor(v, 8, 64));
            if (m == 0) lmax[w][rt * 16 + q * 4 + rg] = v;
        }
    __syncthreads();   // the ONLY block barrier

    // ---- combine center-halves, d = sqrt(x2 - 2*max), block sum ----
    if (t < 64) {
        const int rg2 = t >> 5;        // row-group: waves {0,1} or {2,3}
        const int r = t & 31;
        float M = fmaxf(lmax[rg2 * 2][r], lmax[rg2 * 2 + 1][r]);
        float d = sqrtf(fmaxf(lx2[t] - 2.f * M, 0.f));
        #pragma unroll
        for (int off = 1; off < 64; off <<= 1) d += __shfl_xor(d, off, 64);
        if (t == 0) atomicAdd(out, d * (ALPHA / (float)NROWS));
    }
}

extern "C" void kernel_launch(void* const* d_in, const int* in_sizes, int n_in,
                              void* d_out, int out_size, void* d_ws, size_t ws_size,
                              hipStream_t stream) {
    const float* emb     = (const float*)d_in[0];   // [65536, 256] fp32
    const float* centers = (const float*)d_in[1];   // [512, 256] fp32
    float* out = (float*)d_out;

    float* csqh = (float*)d_ws;                       // 512 * 4 B
    uint4* cbf2 = (uint4*)((char*)d_ws + 2048);       // 256 KB fragment-major bf16

    prep_centers<<<dim3(KC / 8), dim3(256), 0, stream>>>(centers, csqh, cbf2, out);
    kmeans_main<<<dim3(NROWS / 64), dim3(256), 0, stream>>>(emb, cbf2, csqh, out);
}

// Round 5
// 125.006 us; speedup vs baseline: 1.2784x; 1.2784x over previous
//
#include <hip/hip_runtime.h>
#include <hip/hip_bf16.h>

#define NROWS 65536
#define DIM   256
#define KC    512
#define ALPHA 0.05f

#define BM   32    // rows per block
#define SLD  264   // LDS row stride in bf16 elems (528 B = 33*16: 16B-aligned)

typedef __attribute__((ext_vector_type(8))) short bf16x8;
typedef __attribute__((ext_vector_type(4))) float f32x4;

static __device__ __forceinline__ unsigned short f2bf(float f) {
    union { __hip_bfloat16 h; unsigned short u; } c;
    c.h = __float2bfloat16(f);
    return c.u;
}
static __device__ __forceinline__ float bf2f(unsigned short u) {
    union { unsigned short u; __hip_bfloat16 h; } c;
    c.u = u;
    return __bfloat162float(c.h);
}

// Fragment-major center layout (verified r0/r3): col-group cg (16 centers),
// k-step kk, lane l = q*16+m holds center row cg*16+m, elems kk*32+q*8..+7.
// uint4 index = (cg*8+kk)*64 + l.
__global__ void prep_centers(const float* __restrict__ centers,
                             float* __restrict__ csqh,
                             uint4* __restrict__ cbf2,
                             float* __restrict__ out) {
    const int t = threadIdx.x;
    const int r = blockIdx.x * 8 + (t >> 5);  // center row
    const int e = t & 31;                     // 8-elem group within row
    const float4* cv = reinterpret_cast<const float4*>(centers);
    float4 v0 = cv[r * 64 + e * 2];
    float4 v1 = cv[r * 64 + e * 2 + 1];
    float s = v0.x * v0.x + v0.y * v0.y + v0.z * v0.z + v0.w * v0.w
            + v1.x * v1.x + v1.y * v1.y + v1.z * v1.z + v1.w * v1.w;
    unsigned short o[8];
    o[0] = f2bf(v0.x); o[1] = f2bf(v0.y); o[2] = f2bf(v0.z); o[3] = f2bf(v0.w);
    o[4] = f2bf(v1.x); o[5] = f2bf(v1.y); o[6] = f2bf(v1.z); o[7] = f2bf(v1.w);
    const int cg = r >> 4, m = r & 15;
    const int kk = e >> 2, q = e & 3, l = q * 16 + m;
    cbf2[(cg * 8 + kk) * 64 + l] = *reinterpret_cast<uint4*>(o);
    #pragma unroll
    for (int off = 16; off; off >>= 1) s += __shfl_xor(s, off, 64);
    if (e == 0) csqh[r] = 0.5f * s;
    if (blockIdx.x == 0 && t == 0) out[0] = 0.f;  // separate dispatch -> ordered
}

// 32-row blocks, 4 waves: wave w owns rows [blk*32,+32) x cols [w*128,+128).
// A staged once in 17KB LDS (bf16, shared by all 4 waves -> A read once from HBM).
// afr[2][8]=64 VGPR; B streamed per 16-col group, no explicit prefetch arrays
// (scheduler pipelines within the (256,3) cap headroom). 2 barriers total.
__global__ __launch_bounds__(256, 3) void kmeans_main(
    const float* __restrict__ emb,
    const uint4* __restrict__ cbf2,
    const float* __restrict__ csqh_g,
    float* __restrict__ out) {
    __shared__ unsigned short sA[BM * SLD];   // 16896 B
    __shared__ float lmax[4][BM];
    __shared__ float lx2[BM];

    const int t = threadIdx.x;
    const int w = t >> 6;
    const int lane = t & 63;
    const int m = lane & 15;
    const int q = lane >> 4;
    const int row0 = blockIdx.x * BM;

    // ---- stage A tile: fp32 global -> bf16 LDS (coalesced float4) ----
    const float4* embv = reinterpret_cast<const float4*>(emb + (size_t)row0 * DIM);
    #pragma unroll
    for (int i = 0; i < 8; ++i) {
        int f = t + 256 * i;
        int r = f >> 6;
        int c4 = f & 63;
        float4 v = embv[r * 64 + c4];
        ushort4 o;
        o.x = f2bf(v.x); o.y = f2bf(v.y); o.z = f2bf(v.z); o.w = f2bf(v.w);
        *reinterpret_cast<ushort4*>(&sA[r * SLD + c4 * 4]) = o;
    }
    __syncthreads();

    // ---- x_sq per row from staged bf16 (8 threads per row) ----
    {
        int r = t >> 3;
        int g = t & 7;
        const ushort4* p = reinterpret_cast<const ushort4*>(&sA[r * SLD + g * 32]);
        float s = 0.f;
        #pragma unroll
        for (int j = 0; j < 8; ++j) {
            ushort4 u = p[j];
            float a = bf2f(u.x), b = bf2f(u.y), c = bf2f(u.z), d = bf2f(u.w);
            s += a * a + b * b + c * c + d * d;
        }
        s += __shfl_xor(s, 1, 64);
        s += __shfl_xor(s, 2, 64);
        s += __shfl_xor(s, 4, 64);
        if (g == 0) lx2[r] = s;
    }

    // ---- A fragments register-resident: 2 row-tiles x 8 k-steps (64 VGPR) ----
    bf16x8 afr[2][8];
    #pragma unroll
    for (int rt = 0; rt < 2; ++rt)
        #pragma unroll
        for (int k = 0; k < 8; ++k)
            afr[rt][k] = *reinterpret_cast<const bf16x8*>(
                &sA[(rt * 16 + m) * SLD + k * 32 + q * 8]);

    // ---- stream this wave's 8 col-groups (cols w*128 + cg*16 + m) ----
    const bf16x8* cb2 = reinterpret_cast<const bf16x8*>(cbf2);
    float maxv[2][4];
    #pragma unroll
    for (int rt = 0; rt < 2; ++rt)
        #pragma unroll
        for (int rg = 0; rg < 4; ++rg) maxv[rt][rg] = -1e30f;

    #pragma unroll
    for (int cg = 0; cg < 8; ++cg) {
        const int g = w * 8 + cg;              // global 16-col group
        const float ci = -csqh_g[g * 16 + m];  // -c^2/2 of this lane's center
        bf16x8 bcur[8];
        #pragma unroll
        for (int kk = 0; kk < 8; ++kk)
            bcur[kk] = cb2[(g * 8 + kk) * 64 + lane];
        f32x4 acc[2];
        acc[0] = (f32x4){ci, ci, ci, ci};
        acc[1] = (f32x4){ci, ci, ci, ci};
        #pragma unroll
        for (int kk = 0; kk < 8; ++kk)
            #pragma unroll
            for (int rt = 0; rt < 2; ++rt)
                acc[rt] = __builtin_amdgcn_mfma_f32_16x16x32_bf16(
                    afr[rt][kk], bcur[kk], acc[rt], 0, 0, 0);
        #pragma unroll
        for (int rt = 0; rt < 2; ++rt)
            #pragma unroll
            for (int rg = 0; rg < 4; ++rg)
                maxv[rt][rg] = fmaxf(maxv[rt][rg], acc[rt][rg]);
    }

    // ---- per-wave max over its 16 cols (xor over lane&15); row = rt*16+q*4+rg ----
    #pragma unroll
    for (int rt = 0; rt < 2; ++rt)
        #pragma unroll
        for (int rg = 0; rg < 4; ++rg) {
            float v = maxv[rt][rg];
            v = fmaxf(v, __shfl_xor(v, 1, 64));
            v = fmaxf(v, __shfl_xor(v, 2, 64));
            v = fmaxf(v, __shfl_xor(v, 4, 64));
            v = fmaxf(v, __shfl_xor(v, 8, 64));
            if (m == 0) lmax[w][rt * 16 + q * 4 + rg] = v;
        }
    __syncthreads();

    // ---- combine 4 col-quarters, d = sqrt(x2 - 2*max), block sum ----
    if (t < 32) {
        float M = fmaxf(fmaxf(lmax[0][t], lmax[1][t]),
                        fmaxf(lmax[2][t], lmax[3][t]));
        float d = sqrtf(fmaxf(lx2[t] - 2.f * M, 0.f));
        #pragma unroll
        for (int off = 1; off < 32; off <<= 1) d += __shfl_xor(d, off, 64);
        if (t == 0) atomicAdd(out, d * (ALPHA / (float)NROWS));
    }
}

extern "C" void kernel_launch(void* const* d_in, const int* in_sizes, int n_in,
                              void* d_out, int out_size, void* d_ws, size_t ws_size,
                              hipStream_t stream) {
    const float* emb     = (const float*)d_in[0];   // [65536, 256] fp32
    const float* centers = (const float*)d_in[1];   // [512, 256] fp32
    float* out = (float*)d_out;

    float* csqh = (float*)d_ws;                       // 512 * 4 B
    uint4* cbf2 = (uint4*)((char*)d_ws + 2048);       // 256 KB fragment-major bf16

    prep_centers<<<dim3(KC / 8), dim3(256), 0, stream>>>(centers, csqh, cbf2, out);
    kmeans_main<<<dim3(NROWS / BM), dim3(256), 0, stream>>>(emb, cbf2, csqh, out);
}